// Round 1
// 233.267 us; speedup vs baseline: 1.1343x; 1.1343x over previous
//
#include <hip/hip_runtime.h>

#define N_NODES 50000
#define N_EDGES 1600000
#define N_TOTAL (N_EDGES + N_NODES)   // edges + self loops
#define F_IN    32
#define HID     64
#define F_OUT   128
#define G       32                    // dst nodes per gather bucket
#define NB      1563                  // ceil(N_NODES / G)
#define NBIN    196                   // coarse bins: d >> 8 (256 nodes = 8 buckets)
#define CAP1_MAX 10240                // per-bin cap (mean ~8420 + ~20 sigma)
#define OVF_CAP 16384
#define W1WIN   4096                  // pass-1 window (edges per block)

// workspace layout (u32 units), ~14.5 MB max (unchanged from previous round):
#define OFF_QBF   0
#define OFF_CUR1  (N_NODES * 32)
#define OFF_OVFC  (OFF_CUR1 + NBIN * 16)
#define OFF_CELLB (OFF_OVFC + 16)
#define OFF_CELLC (OFF_CELLB + NB)
#define OFF_OVF   (OFF_CELLC + NB + 2)
#define OFF_BIN   (OFF_OVF + OVF_CAP)
#define NCLR      (NBIN * 16 + 16)    // words to zero (cur1 + ovfc)

typedef __attribute__((ext_vector_type(2))) _Float16 h2f;    // packed half2 (1 VGPR)
typedef __attribute__((ext_vector_type(8))) _Float16 half8;  // MFMA f16 frag (4 VGPRs)
typedef __attribute__((ext_vector_type(4))) float v4f;

__device__ __forceinline__ unsigned f2h2(float a, float b) {   // pack 2 f16 (RNE)
    h2f v;
    v.x = (_Float16)a; v.y = (_Float16)b;
    return __builtin_bit_cast(unsigned, v);
}

// relu(a - b) on packed f16 pairs: v_pk_add_f16(neg) + v_pk_max_f16
__device__ __forceinline__ unsigned hsubmax0(unsigned a, unsigned b) {
    h2f x = __builtin_bit_cast(h2f, a) - __builtin_bit_cast(h2f, b);
    h2f z = {(_Float16)0.f, (_Float16)0.f};
    x = __builtin_elementwise_max(x, z);
    return __builtin_bit_cast(unsigned, x);
}

__device__ __forceinline__ float h2lo(unsigned u) { return (float)__builtin_bit_cast(h2f, u).x; }
__device__ __forceinline__ float h2hi(unsigned u) { return (float)__builtin_bit_cast(h2f, u).y; }
__device__ __forceinline__ float f16r(float x)    { return (float)(_Float16)x; }

// Wave-local LDS handoff fence: waits this wave's own DS ops, orders the
// surrounding LDS accesses (asm "memory" clobber) and pins scheduling
// (rule: sched_barrier(0) right after an inline-asm lgkmcnt wait).
#define WAVE_FENCE() do { asm volatile("s_waitcnt lgkmcnt(0)" ::: "memory"); \
                          __builtin_amdgcn_sched_barrier(0); } while (0)

// ---------------------------------------------------------------------------
// Kernel A: Q'[n] = b1 + x_n @ W1[0:32,:] + pos_n @ W1[32:35,:], packed f16.
// (pos contribution folded in: per-edge layer-1 becomes relu(Q'_src - R_dst).)
// Also zeros pass-1 cursors.
// ---------------------------------------------------------------------------
__global__ __launch_bounds__(256) void node_pre_kernel(
    const float* __restrict__ x, const float* __restrict__ pos,
    const float* __restrict__ W1, const float* __restrict__ b1,
    unsigned* __restrict__ qbf, unsigned* __restrict__ clr)
{
    const int n = blockIdx.x * 256 + threadIdx.x;
    if (n < NCLR) clr[n] = 0u;
    if (n >= N_NODES) return;

    float acc[HID];
    #pragma unroll
    for (int k = 0; k < HID; ++k) acc[k] = b1[k];

    const float4* x4 = (const float4*)(x + (long long)n * F_IN);
    #pragma unroll 1
    for (int c4 = 0; c4 < F_IN / 4; ++c4) {
        const float4 v = x4[c4];
        const float mv[4] = {v.x, v.y, v.z, v.w};
        #pragma unroll
        for (int qq = 0; qq < 4; ++qq) {
            const float* wrow = W1 + (c4 * 4 + qq) * HID;   // wave-uniform
            #pragma unroll
            for (int k = 0; k < HID; ++k) acc[k] = fmaf(mv[qq], wrow[k], acc[k]);
        }
    }
    #pragma unroll
    for (int a = 0; a < 3; ++a) {
        const float pp = pos[n * 3 + a];
        const float* wrow = W1 + (F_IN + a) * HID;          // wave-uniform
        #pragma unroll
        for (int k = 0; k < HID; ++k) acc[k] = fmaf(pp, wrow[k], acc[k]);
    }

    uint4* o4 = (uint4*)(qbf + (unsigned)n * 32u);
    #pragma unroll
    for (int j4 = 0; j4 < 8; ++j4)
        o4[j4] = make_uint4(f2h2(acc[j4*8+0], acc[j4*8+1]),
                            f2h2(acc[j4*8+2], acc[j4*8+3]),
                            f2h2(acc[j4*8+4], acc[j4*8+5]),
                            f2h2(acc[j4*8+6], acc[j4*8+7]));
}

// ---------------------------------------------------------------------------
// Kernel B1: pass-1 binning (unchanged). Entry format: (d << 16) | s.
// ---------------------------------------------------------------------------
__global__ __launch_bounds__(1024) void bin_kernel(
    const int* __restrict__ ei, unsigned* __restrict__ cur1,
    unsigned* __restrict__ bin1, unsigned* __restrict__ ovfc,
    unsigned* __restrict__ ovf, int cap1)
{
    __shared__ unsigned stage[W1WIN];       // 16 KB
    __shared__ unsigned binid[W1WIN];       // 16 KB
    __shared__ unsigned hist[NBIN], startp[NBIN + 1], gbase[NBIN];

    const int t = threadIdx.x;
    const int wbase = blockIdx.x * W1WIN;

    for (int i = t; i < NBIN; i += 1024) hist[i] = 0u;
    __syncthreads();

    unsigned ev[4]; int bv[4]; unsigned rv[4]; bool val[4];
    #pragma unroll
    for (int k = 0; k < 4; ++k) {
        const int idx = wbase + k * 1024 + t;
        val[k] = idx < N_TOTAL;
        if (val[k]) {
            int s, d;
            if (idx < N_EDGES) { s = ei[idx]; d = ei[N_EDGES + idx]; }
            else               { s = d = idx - N_EDGES; }    // self loop
            ev[k] = ((unsigned)d << 16) | (unsigned)s;
            bv[k] = d >> 8;
            rv[k] = atomicAdd(&hist[bv[k]], 1u);
        }
    }
    __syncthreads();

    if (t == 0) {
        unsigned run = 0;
        #pragma unroll 1
        for (int b = 0; b < NBIN; ++b) { startp[b] = run; run += hist[b]; }
        startp[NBIN] = run;
    }
    __syncthreads();
    if (t < NBIN && hist[t]) gbase[t] = atomicAdd(&cur1[t * 16], hist[t]);

    #pragma unroll
    for (int k = 0; k < 4; ++k)
        if (val[k]) {
            const unsigned pos = startp[bv[k]] + rv[k];
            stage[pos] = ev[k]; binid[pos] = (unsigned)bv[k];
        }
    __syncthreads();

    const unsigned total = startp[NBIN];
    for (unsigned i = t; i < total; i += 1024u) {
        const unsigned b = binid[i];
        const unsigned gp = gbase[b] + (i - startp[b]);
        if (gp < (unsigned)cap1) bin1[b * (unsigned)cap1 + gp] = stage[i];
        else {
            const unsigned qo = atomicAdd(ovfc, 1u);
            if (qo < OVF_CAP) ovf[qo] = stage[i];
        }
    }
}

// ---------------------------------------------------------------------------
// Kernel B2: pass-2 refine (unchanged). Output entry: (dloc5 << 16) | s.
// ---------------------------------------------------------------------------
__global__ __launch_bounds__(1024) void refine_kernel(
    unsigned* __restrict__ bin1, const unsigned* __restrict__ cur1,
    unsigned* __restrict__ cellbase, unsigned* __restrict__ cellcnt, int cap1)
{
    __shared__ unsigned ebuf[CAP1_MAX];     // 40 KB
    __shared__ unsigned cnt32[8 * 32];      // [fb][rep], bank = rep
    __shared__ unsigned startp[8];

    const int bb = blockIdx.x, t = threadIdx.x;
    const unsigned n1 = min(cur1[bb * 16], (unsigned)cap1);
    const unsigned base1 = (unsigned)bb * (unsigned)cap1;
    const int rep = t & 31;

    for (int i = t; i < 8 * 32; i += 1024) cnt32[i] = 0u;
    __syncthreads();

    for (unsigned i = t; i < n1; i += 1024u) {
        const unsigned e = bin1[base1 + i];
        ebuf[i] = e;
        const int fb = (int)((e >> 21) & 7u);   // (d & 255) >> 5
        atomicAdd(&cnt32[fb * 32 + rep], 1u);
    }
    __syncthreads();

    if (t == 0) {
        unsigned run = 0;
        #pragma unroll
        for (int fb = 0; fb < 8; ++fb) {
            startp[fb] = run;
            unsigned s2 = run;
            #pragma unroll
            for (int r = 0; r < 32; ++r) {      // cnt32 becomes write cursors
                const unsigned c = cnt32[fb * 32 + r];
                cnt32[fb * 32 + r] = s2; s2 += c;
            }
            run = s2;
        }
    }
    __syncthreads();

    if (t < 8) {
        const int cell = bb * 8 + t;
        if (cell < NB) {
            cellbase[cell] = base1 + startp[t];
            cellcnt[cell]  = ((t < 7) ? startp[t + 1] : n1) - startp[t];
        }
    }

    for (unsigned i = t; i < n1; i += 1024u) {
        const unsigned e = ebuf[i];
        const int fb = (int)((e >> 21) & 7u);
        const unsigned p = atomicAdd(&cnt32[fb * 32 + rep], 1u);
        bin1[base1 + p] = (((e >> 16) & 31u) << 16) | (e & 0xFFFFu);
    }
}

// ---------------------------------------------------------------------------
// Kernel C: gather. One block (4 waves) per 32-dst bucket.
//   layer1: h1 = relu_f16(Q'_src - R_dst)  (2 pk ops / 2 channels)
//   R_dst (32 rows) built once per block into LDS (f16 pairs, xor-swizzled)
//   layer2: 16x16x32 f16 MFMA, +b2/relu, LDS atomicMax agg, coalesced store.
// NO block barriers in the main loop: all LDS handoffs are wave-private
// (ast[w] staging), fenced with wave-local lgkmcnt(0)+sched_barrier.
// Invalid tail lanes atomic into dump row G (discarded) -> branchless epilogue.
// ---------------------------------------------------------------------------
__global__ __launch_bounds__(256, 4) void gather_kernel(
    const unsigned* __restrict__ qbf,   // [N,32] packed f16 Q'
    const float* __restrict__ pos,
    const unsigned* __restrict__ cellbase,
    const unsigned* __restrict__ cellcnt,
    const unsigned* __restrict__ bkt,
    const float* __restrict__ W1p,      // W1 rows 32..34, [3, 64]
    const float* __restrict__ W2, const float* __restrict__ b2,
    float* __restrict__ out)
{
    __shared__ unsigned aggs[(G + 1) * HID];  // 8448 B (+1 dump row)
    __shared__ unsigned w2t[64 * 32];         // 8 KB: W2^T f16 pairs, xor-swizzled
    __shared__ unsigned rlds[G * 32];         // 4 KB: R[dst] f16 pairs, xor-swizzled
    __shared__ unsigned ast[4][64 * 16];      // 16 KB: per-wave A-stage (one k-half)

    const int t = threadIdx.x, lane = t & 63, w = t >> 6;
    const int q = lane >> 4, m15 = lane & 15;
    const int b = blockIdx.x;
    const unsigned cnt  = cellcnt[b];
    const unsigned base = cellbase[b];

    for (int i = t; i < (G + 1) * HID; i += 256) aggs[i] = 0u;
    for (int i = t; i < 64 * 32; i += 256) {            // W2^T -> f16 LDS (xor)
        const int nn = i >> 5, ku = i & 31;             // k-pair index
        w2t[(nn << 5) + ((((ku >> 2) ^ (nn & 7)) << 2) | (ku & 3))] =
            f2h2(W2[(2 * ku) * HID + nn], W2[(2 * ku + 1) * HID + nn]);
    }
    for (int i = t; i < G * 32; i += 256) {             // R[dl][k] = pos_dl @ W1p
        const int dl = i >> 5, k2 = i & 31;
        const int node = b * G + dl;
        float v0 = 0.f, v1 = 0.f;
        if (node < N_NODES) {
            #pragma unroll
            for (int a = 0; a < 3; ++a) {
                const float pp = pos[node * 3 + a];
                v0 = fmaf(pp, W1p[a * HID + 2 * k2], v0);
                v1 = fmaf(pp, W1p[a * HID + 2 * k2 + 1], v1);
            }
        }
        rlds[(dl << 5) + ((((k2 >> 2) ^ (dl & 7)) << 2) | (k2 & 3))] = f2h2(v0, v1);
    }
    __syncthreads();

    float b2v[4];
    #pragma unroll
    for (int nt = 0; nt < 4; ++nt) b2v[nt] = b2[nt * 16 + m15];

    unsigned* aw = ast[w];
    const int axw = ((lane >> 1) & 3) << 2;     // write-side chunk xor (u32 units)
    const int axr = ((m15 >> 1) & 3) << 2;      // read-side chunk xor (row=mt*16+m15)
    const unsigned nit = (cnt + 255u) >> 8;     // block-uniform iteration count

    #pragma unroll 1
    for (unsigned it = 0; it < nit; ++it) {
        const unsigned off = it * 256u + (unsigned)w * 64u;
        const unsigned rem = (off < cnt) ? min(64u, cnt - off) : 0u;
        const unsigned f = off + (unsigned)lane;
        unsigned pent = 0u;
        if (f < cnt) pent = bkt[base + f];
        const int s = (int)(pent & 0xFFFFu), dl = (int)(pent >> 16);

        // Q' row: 8 x b128 issued up front (outstanding during layer-1)
        const uint4* qr = (const uint4*)(qbf + (unsigned)s * 32u);
        uint4 qv[8];
        #pragma unroll
        for (int i = 0; i < 8; ++i) qv[i] = qr[i];

        const int rbase = (dl << 5), rx = dl & 7;

        half8 a0[4], a1[4];
        #pragma unroll
        for (int hf = 0; hf < 2; ++hf) {
            #pragma unroll
            for (int j4 = 0; j4 < 4; ++j4) {
                const uint4 r4 = *(const uint4*)(
                    rlds + rbase + (((hf * 4 + j4) ^ rx) << 2));
                const uint4 qq = qv[hf * 4 + j4];
                uint4 hh;
                hh.x = hsubmax0(qq.x, r4.x);
                hh.y = hsubmax0(qq.y, r4.y);
                hh.z = hsubmax0(qq.z, r4.z);
                hh.w = hsubmax0(qq.w, r4.w);
                *(uint4*)(aw + (lane << 4) + ((j4 << 2) ^ axw)) = hh;
            }
            WAVE_FENCE();                       // stage writes -> cross-lane reads
            half8* af = hf ? a1 : a0;
            #pragma unroll
            for (int mt = 0; mt < 4; ++mt)
                af[mt] = *(const half8*)(
                    aw + ((mt * 16 + m15) << 4) + ((q << 2) ^ axr));
            WAVE_FENCE();                       // reads done -> next overwrite ok
        }

        // dst-locals for the C rows this lane owns (shfl: dl lives in lane er)
        int dsh[16];
        #pragma unroll
        for (int i = 0; i < 16; ++i) {
            const int er = (i >> 2) * 16 + q * 4 + (i & 3);
            const int dv = __shfl(dl, er, 64);
            dsh[i] = ((((unsigned)er < rem) ? dv : G) << 6) + m15;  // dump row G if invalid
        }

        // ---- MFMA layer 2 + epilogue, in two 32-channel halves ----
        #pragma unroll
        for (int h = 0; h < 2; ++h) {
            half8 bf[2][2];    // [ntl][ks]
            const int nx = m15 & 7;
            #pragma unroll
            for (int ntl = 0; ntl < 2; ++ntl) {
                const int nn = (2 * h + ntl) * 16 + m15;
                #pragma unroll
                for (int ks = 0; ks < 2; ++ks)
                    bf[ntl][ks] = *(const half8*)(
                        w2t + (nn << 5) + (((ks * 4 + q) ^ nx) << 2));
            }
            v4f c[4][2] = {};
            #pragma unroll
            for (int mt = 0; mt < 4; ++mt)
                #pragma unroll
                for (int ntl = 0; ntl < 2; ++ntl) {
                    c[mt][ntl] = __builtin_amdgcn_mfma_f32_16x16x32_f16(
                        a0[mt], bf[ntl][0], c[mt][ntl], 0, 0, 0);
                    c[mt][ntl] = __builtin_amdgcn_mfma_f32_16x16x32_f16(
                        a1[mt], bf[ntl][1], c[mt][ntl], 0, 0, 0);
                }
            #pragma unroll
            for (int mt = 0; mt < 4; ++mt)
                #pragma unroll
                for (int r = 0; r < 4; ++r) {
                    const int ab = dsh[mt * 4 + r];
                    #pragma unroll
                    for (int ntl = 0; ntl < 2; ++ntl) {
                        const int nt = 2 * h + ntl;
                        const float hv = fmaxf(c[mt][ntl][r] + b2v[nt], 0.f);
                        atomicMax(&aggs[ab + nt * 16], __float_as_uint(hv));
                    }
                }
        }
    }
    __syncthreads();

    for (int i = t; i < G * HID; i += 256) {
        const int row = i >> 6, ch = i & 63, n = b * G + row;
        if (n < N_NODES)
            out[(long long)n * F_OUT + HID + ch] = __uint_as_float(aggs[i]);
    }
}

// ---------------------------------------------------------------------------
// Kernel D: overflow fixup (~0 edges in practice; correct for any count).
// Numerics match the MFMA path: h1 = relu(f16(Q' - f16(R))), W2 in f16.
// Entry: (d<<16)|s with full node id d.
// ---------------------------------------------------------------------------
__global__ __launch_bounds__(64) void ovf_kernel(
    const unsigned* __restrict__ qbf, const float* __restrict__ pos,
    const unsigned* __restrict__ ovfc, const unsigned* __restrict__ ovf,
    const float* __restrict__ W1p, const float* __restrict__ W2,
    const float* __restrict__ b2, unsigned* __restrict__ aggbits)
{
    const unsigned n = min(*ovfc, (unsigned)OVF_CAP);
    for (unsigned i = blockIdx.x * 64 + threadIdx.x; i < n; i += gridDim.x * 64) {
        const unsigned p = ovf[i];
        const int s = (int)(p & 0xFFFFu), d = (int)(p >> 16);
        float h1[HID];
        #pragma unroll 1
        for (int k = 0; k < HID; ++k) {
            const unsigned u = qbf[s * 32 + (k >> 1)];
            const float qp = (k & 1) ? h2hi(u) : h2lo(u);
            float r = 0.f;
            #pragma unroll 1
            for (int a = 0; a < 3; ++a) r = fmaf(pos[d * 3 + a], W1p[a * HID + k], r);
            h1[k] = fmaxf(f16r(qp - f16r(r)), 0.f);
        }
        unsigned* ap = aggbits + (long long)d * F_OUT + HID;
        #pragma unroll 1
        for (int k = 0; k < HID; ++k) {
            float a2 = b2[k];
            #pragma unroll 1
            for (int j = 0; j < HID; ++j)
                a2 = fmaf(h1[j], f16r(W2[j * HID + k]), a2);
            a2 = fmaxf(a2, 0.f);
            atomicMax(ap + k, __float_as_uint(a2));
        }
    }
}

// ---------------------------------------------------------------------------
// Kernel E: out[n] = agg[n] @ Wg + bg, in place (unchanged).
// ---------------------------------------------------------------------------
__global__ __launch_bounds__(256) void out_gemm_kernel(
    float* __restrict__ out,            // [N_NODES, 128]
    const float* __restrict__ Wg,       // [HID, F_OUT]
    const float* __restrict__ bg)       // [F_OUT]
{
    const int lane = threadIdx.x & 63;
    const int wave = blockIdx.x * (blockDim.x >> 6) + (threadIdx.x >> 6);
    const int nwav = gridDim.x * (blockDim.x >> 6);

    float w1r[HID], w2r[HID];
    #pragma unroll
    for (int j = 0; j < HID; ++j) {
        w1r[j] = Wg[j * F_OUT + lane];
        w2r[j] = Wg[j * F_OUT + 64 + lane];
    }
    const float bga = bg[lane];
    const float bgb = bg[64 + lane];

    for (int n = wave; n < N_NODES; n += nwav) {
        float* row = out + (long long)n * F_OUT;
        const float a = row[64 + lane];
        float y1 = bga, y2 = bgb;
        #pragma unroll
        for (int j = 0; j < HID; ++j) {
            const float aj = __shfl(a, j, 64);
            y1 = fmaf(aj, w1r[j], y1);
            y2 = fmaf(aj, w2r[j], y2);
        }
        row[lane]      = y1;
        row[64 + lane] = y2;
    }
}

extern "C" void kernel_launch(void* const* d_in, const int* in_sizes, int n_in,
                              void* d_out, int out_size, void* d_ws, size_t ws_size,
                              hipStream_t stream) {
    const float* x   = (const float*)d_in[0];
    const float* pos = (const float*)d_in[1];
    const int*   ei  = (const int*)d_in[2];    // harness delivers integers as int32
    const float* W1  = (const float*)d_in[3];
    const float* b1  = (const float*)d_in[4];
    const float* W2  = (const float*)d_in[5];
    const float* b2  = (const float*)d_in[6];
    const float* Wg  = (const float*)d_in[7];
    const float* bg  = (const float*)d_in[8];
    float* out = (float*)d_out;

    unsigned* ws    = (unsigned*)d_ws;
    unsigned* qbf   = ws + OFF_QBF;
    unsigned* cur1  = ws + OFF_CUR1;
    unsigned* ovfc  = ws + OFF_OVFC;
    unsigned* cellb = ws + OFF_CELLB;
    unsigned* cellc = ws + OFF_CELLC;
    unsigned* ovf   = ws + OFF_OVF;
    unsigned* bin1  = ws + OFF_BIN;

    // per-bin capacity from available workspace (overflow path correct anyway)
    long long avail = (long long)(ws_size / 4) - OFF_BIN;
    int cap1 = (int)(avail / NBIN);
    if (cap1 > CAP1_MAX) cap1 = CAP1_MAX;
    if (cap1 < 2048) cap1 = 2048;

    node_pre_kernel<<<(N_NODES + 255) / 256, 256, 0, stream>>>(x, pos, W1, b1, qbf, cur1);
    bin_kernel<<<(N_TOTAL + W1WIN - 1) / W1WIN, 1024, 0, stream>>>(
        ei, cur1, bin1, ovfc, ovf, cap1);
    refine_kernel<<<NBIN, 1024, 0, stream>>>(bin1, cur1, cellb, cellc, cap1);
    gather_kernel<<<NB, 256, 0, stream>>>(
        qbf, pos, cellb, cellc, bin1, W1 + F_IN * HID, W2, b2, out);
    ovf_kernel<<<32, 64, 0, stream>>>(
        qbf, pos, ovfc, ovf, W1 + F_IN * HID, W2, b2, (unsigned*)out);
    out_gemm_kernel<<<512, 256, 0, stream>>>(out, Wg, bg);
}